// Round 12
// baseline (3097.456 us; speedup 1.0000x reference)
//
#include <hip/hip_runtime.h>
#include <math.h>

#define B 4
#define N 32768
#define D 131
#define S 1024
#define RAD2 0.1f      // reference compares d2 <= RADIUS (=0.1) on SQUARED distance
#define G 8            // FPS participant blocks per batch
#define TPB 256        // threads per block
#define SLICE (N / G)  // 4096 points per participant
#define PPT 16         // SLICE / TPB
#define NB_TOTAL 512   // total blocks in fused kernel
#define NFPS_TOT (B * G)            // 32
#define NCOPY (NB_TOTAL - NFPS_TOT) // 480 copy workers (exactly 32 always claim FPS)
#define SLOT_STRIDE 8  // u64s per slot (64B padding)

// ---------------------------------------------------------------------------
// Pack pts = x[:,:,:3] into SoA (px|py|pz) AND packed float4 {x,y,z,0}.
// ---------------------------------------------------------------------------
__global__ void pack_kernel(const float* __restrict__ x, float* __restrict__ ws) {
    int i = blockIdx.x * blockDim.x + threadIdx.x;
    if (i < B * N) {
        const float* __restrict__ s = x + (size_t)i * D;
        float a = s[0], bb = s[1], c = s[2];
        ws[i]             = a;
        ws[B * N + i]     = bb;
        ws[2 * B * N + i] = c;
        float4* w4 = (float4*)(ws + (size_t)3 * B * N);
        w4[i] = make_float4(a, bb, c, 0.0f);
    }
}

// sc0 load: bypasses L1, served by the XCD-local L2.
__device__ inline unsigned long long ld_sc0(const unsigned long long* p) {
    unsigned long long v;
    asm volatile("global_load_dwordx2 %0, %1, off sc0\n\t"
                 "s_waitcnt vmcnt(0)"
                 : "=v"(v) : "v"(p) : "memory");
    return v;
}
// sc0 store: write-through to the XCD-local L2 (GCN vector L1 is write-through;
// sc0 makes the L1 bypass explicit).
__device__ inline void st_sc0(unsigned long long* p, unsigned long long v) {
    asm volatile("global_store_dwordx2 %0, %1, off sc0" :: "v"(p), "v"(v) : "memory");
}
__device__ inline int get_xcc() {
    int v;
    asm("s_getreg_b32 %0, hwreg(HW_REG_XCC_ID)" : "=s"(v));   // HW-verified (m09)
    return v & 7;
}

// ---------------------------------------------------------------------------
// Fused FPS + copy with XCD-VERIFIED role assignment. 512 blocks x 256 thr.
// Registration: first 64 blocks (agent-scope counter) publish their XCC_ID;
// all registrants poll the 64 entries, then run the SAME deterministic
// assignment: 4 most-populated XCDs -> batches 0..3, 8 same-XCD blocks each
// (proto=0: L2/sc0 rendezvous). Under-filled batches get leftover blocks and
// proto=1 (agent/L3 rendezvous, the proven R9 path). Everyone else copies x.
// Per step (R9 skeleton): LDS-coords compute -> wave butterfly -> LDS wave
// keys -> barrier -> wave0: blockkey -> slot store (sc0 [+agent belt]) ->
// poll 8 slots (sc0 with 1/16 agent liveness mix, or pure agent for proto=1)
// -> candidate-coord prefetch overlapped with 3-stage reduce -> ballot/shfl
// winner coords -> LDS {coords,tag} bcast; waves 1..3 spin on the LDS tag.
// Key: [f32 val:32][32767-idx:15][0:6][tag=s+1:11]; equal tags => u64 max =
// (max val, then min idx) = exact reference tie-break.
// Safety: writer always issues the agent store too; stale L2 lines can only
// show OLD tags (ignored); double-buffered slots as before. Output is
// identical regardless of which physical blocks claim which role.
// ---------------------------------------------------------------------------
__launch_bounds__(TPB)
__global__ void fps_copy_kernel(const float* __restrict__ x,
                                const float* __restrict__ ws,
                                unsigned* __restrict__ ctl,               // [0]=reg_cnt [1]=copy_cnt [16..79]=reg
                                unsigned long long* __restrict__ slots_all, // [B][2][G] 64B-strided
                                float* __restrict__ out_idx,
                                int* __restrict__ idx_int,
                                float* __restrict__ out_x) {
    const int t = threadIdx.x;
    const int lane = t & 63;
    const int w = t >> 6;                   // wave 0..3

    __shared__ float s_x[SLICE], s_y[SLICE], s_z[SLICE];   // 48 KB coords
    __shared__ unsigned long long s_wk[2][4];              // wave keys (dbuf)
    __shared__ float s_bc[3];                              // bcast centroid
    __shared__ unsigned s_tag;                             // monotone step tag
    __shared__ unsigned s_regv[64];
    __shared__ int s_info[4];       // [0] role (0 fps / 1 copy), [1] b, [2] g, [3] proto
    __shared__ int s_copyid;

    // ---------------- registration & role assignment ----------------
    const int xcc = get_xcc();
    if (t == 0) {
        unsigned c = __hip_atomic_fetch_add(&ctl[0], 1u, __ATOMIC_RELAXED,
                                            __HIP_MEMORY_SCOPE_AGENT);
        if (c < 64) {
            __hip_atomic_store(&ctl[16 + c], 0x100u | (unsigned)xcc,
                               __ATOMIC_RELAXED, __HIP_MEMORY_SCOPE_AGENT);
            s_info[0] = (int)c;     // provisional: registrant id
        } else {
            s_info[0] = -1;
        }
    }
    __syncthreads();
    const int myreg = s_info[0];

    if (myreg >= 0) {                       // block-uniform branch
        if (t < 64) {
            unsigned v;
            do { v = __hip_atomic_load(&ctl[16 + t], __ATOMIC_RELAXED,
                                       __HIP_MEMORY_SCOPE_AGENT); }
            while (!(v & 0x100u));
            s_regv[t] = v & 7u;
        }
        __syncthreads();
        if (t == 0) {
            int cnt[8] = {0,0,0,0,0,0,0,0};
            for (int i = 0; i < 64; ++i) cnt[s_regv[i]]++;
            int ord[8] = {0,1,2,3,4,5,6,7};
            for (int a2 = 0; a2 < 8; ++a2)           // sort by (cnt desc, xcd asc)
                for (int b2 = a2 + 1; b2 < 8; ++b2)
                    if (cnt[ord[b2]] > cnt[ord[a2]]) { int tmp = ord[a2]; ord[a2] = ord[b2]; ord[b2] = tmp; }
            int asb[64], asg[64], proto[4];
            for (int i = 0; i < 64; ++i) asb[i] = -1;
            for (int k = 0; k < 4; ++k) {
                const int X = ord[k];
                int gg = 0;
                for (int i = 0; i < 64 && gg < G; ++i)
                    if (asb[i] < 0 && (int)s_regv[i] == X) { asb[i] = k; asg[i] = gg++; }
                proto[k] = (gg == G) ? 0 : 1;        // full same-XCD group -> L2 path
                for (int i = 0; i < 64 && gg < G; ++i)
                    if (asb[i] < 0) { asb[i] = k; asg[i] = gg++; }
            }
            if (asb[myreg] >= 0) {
                s_info[0] = 0; s_info[1] = asb[myreg];
                s_info[2] = asg[myreg]; s_info[3] = proto[asb[myreg]];
            } else {
                s_info[0] = 1;
            }
        }
        __syncthreads();
    } else {
        if (t == 0) s_info[0] = 1;
        __syncthreads();
    }

    if (s_info[0] == 1) {
        // ---------------- copy role: claim a chunk, grid-stride ----------------
        if (t == 0)
            s_copyid = (int)__hip_atomic_fetch_add(&ctl[1], 1u, __ATOMIC_RELAXED,
                                                   __HIP_MEMORY_SCOPE_AGENT);
        __syncthreads();
        const int ci = s_copyid;
        const size_t total4 = (size_t)B * N * D / 4;
        const float4* __restrict__ src = (const float4*)x;
        float4* __restrict__ dst = (float4*)out_x;
        for (size_t i = (size_t)ci * TPB + t; i < total4; i += (size_t)NCOPY * TPB)
            dst[i] = src[i];
        return;
    }

    // ---------------- FPS role ----------------
    const int b = s_info[1];
    const int g = s_info[2];
    const int proto = s_info[3];

    const float* __restrict__ px = ws + (size_t)b * N;
    const float* __restrict__ py = ws + (size_t)(B + b) * N;
    const float* __restrict__ pz = ws + (size_t)(2 * B + b) * N;
    const float4* __restrict__ p4 = (const float4*)(ws + (size_t)3 * B * N) + (size_t)b * N;
    unsigned long long* __restrict__ slots = slots_all + (size_t)b * 2 * G * SLOT_STRIDE;

    const int base = g * SLICE;
    float lcl[PPT];
    #pragma unroll
    for (int i = 0; i < PPT / 2; ++i) {
        const int l = 2 * t + 2 * TPB * i;          // [0, 4096)
        *(float2*)&s_x[l] = *(const float2*)&px[base + l];
        *(float2*)&s_y[l] = *(const float2*)&py[base + l];
        *(float2*)&s_z[l] = *(const float2*)&pz[base + l];
        lcl[2*i] = INFINITY; lcl[2*i+1] = INFINITY;
    }
    if (t == 0) s_tag = 0;
    __syncthreads();

    float4 cq = p4[0];
    float cx = cq.x, cy = cq.y, cz = cq.z;   // centroid 0 (ref starts at sel=0)

    for (int s = 0; s < S; ++s) {
        float best = -INFINITY;
        int   bidx = 0;
        #pragma unroll
        for (int i = 0; i < PPT / 2; ++i) {
            const int l = 2 * t + 2 * TPB * i;
            float2 vx = *(const float2*)&s_x[l];
            float2 vy = *(const float2*)&s_y[l];
            float2 vz = *(const float2*)&s_z[l];
            {
                float dx = __fsub_rn(cx, vx.x);
                float dy = __fsub_rn(cy, vy.x);
                float dz = __fsub_rn(cz, vz.x);
                float d2 = __fadd_rn(__fadd_rn(__fmul_rn(dx, dx), __fmul_rn(dy, dy)),
                                     __fmul_rn(dz, dz));
                float c = fminf(lcl[2*i], d2);
                lcl[2*i] = c;
                if (c > best) { best = c; bidx = base + l; }   // strict >: smallest p
            }
            {
                float dx = __fsub_rn(cx, vx.y);
                float dy = __fsub_rn(cy, vy.y);
                float dz = __fsub_rn(cz, vz.y);
                float d2 = __fadd_rn(__fadd_rn(__fmul_rn(dx, dx), __fmul_rn(dy, dy)),
                                     __fmul_rn(dz, dz));
                float c = fminf(lcl[2*i+1], d2);
                lcl[2*i+1] = c;
                if (c > best) { best = c; bidx = base + l + 1; }
            }
        }

        // intra-wave butterfly argmax on (value, smallest idx)
        unsigned hi  = __float_as_uint(best);
        unsigned lo2 = (unsigned)(32767 - bidx);
        #define FPS_COMBINE(OHI, OLO) \
            { unsigned _oh = (OHI), _ol = (OLO); \
              if (_oh > hi || (_oh == hi && _ol > lo2)) { hi = _oh; lo2 = _ol; } }
        { unsigned a = (unsigned)__builtin_amdgcn_update_dpp(0, (int)hi, 0xB1, 0xf, 0xf, true);
          unsigned c2 = (unsigned)__builtin_amdgcn_update_dpp(0, (int)lo2, 0xB1, 0xf, 0xf, true);
          FPS_COMBINE(a, c2); }
        { unsigned a = (unsigned)__builtin_amdgcn_update_dpp(0, (int)hi, 0x4E, 0xf, 0xf, true);
          unsigned c2 = (unsigned)__builtin_amdgcn_update_dpp(0, (int)lo2, 0x4E, 0xf, 0xf, true);
          FPS_COMBINE(a, c2); }
        { unsigned a = (unsigned)__builtin_amdgcn_update_dpp(0, (int)hi, 0x141, 0xf, 0xf, true);
          unsigned c2 = (unsigned)__builtin_amdgcn_update_dpp(0, (int)lo2, 0x141, 0xf, 0xf, true);
          FPS_COMBINE(a, c2); }
        { unsigned a = (unsigned)__builtin_amdgcn_update_dpp(0, (int)hi, 0x140, 0xf, 0xf, true);
          unsigned c2 = (unsigned)__builtin_amdgcn_update_dpp(0, (int)lo2, 0x140, 0xf, 0xf, true);
          FPS_COMBINE(a, c2); }
        { unsigned a = (unsigned)__builtin_amdgcn_ds_swizzle((int)hi, 0x401F);
          unsigned c2 = (unsigned)__builtin_amdgcn_ds_swizzle((int)lo2, 0x401F);
          FPS_COMBINE(a, c2); }
        { unsigned a = (unsigned)__shfl_xor((int)hi, 32, 64);
          unsigned c2 = (unsigned)__shfl_xor((int)lo2, 32, 64);
          FPS_COMBINE(a, c2); }
        #undef FPS_COMBINE

        const int buf = s & 1;
        const unsigned tag = (unsigned)(s + 1);
        const unsigned long long mykey = ((unsigned long long)hi << 32) |
                                         ((unsigned long long)lo2 << 17) | tag;
        if (lane == 0) s_wk[buf][w] = mykey;
        __syncthreads();                             // the ONLY barrier per step

        if (w == 0) {
            unsigned long long bk = s_wk[buf][0];
            #pragma unroll
            for (int j = 1; j < 4; ++j) { unsigned long long v = s_wk[buf][j]; if (v > bk) bk = v; }
            unsigned long long* wslot = &slots[((size_t)buf * G + g) * SLOT_STRIDE];
            if (lane == 0) {
                if (proto == 0) st_sc0(wslot, bk);          // fast path: XCD-local L2
                __hip_atomic_store(wslot, bk, __ATOMIC_RELAXED,
                                   __HIP_MEMORY_SCOPE_AGENT);   // truth/liveness path
            }

            // poll the G slots: lane i watches slot i&7
            unsigned long long* myslot = &slots[((size_t)buf * G + (lane & 7)) * SLOT_STRIDE];
            unsigned long long kko;
            if (proto == 0) {
                int it = 0;
                for (;;) {
                    kko = (++it & 15) ? ld_sc0(myslot)
                                      : __hip_atomic_load(myslot, __ATOMIC_RELAXED,
                                                          __HIP_MEMORY_SCOPE_AGENT);
                    if (!__any((unsigned)(kko & 0x7FFull) != tag)) break;
                }
            } else {
                for (;;) {
                    kko = __hip_atomic_load(myslot, __ATOMIC_RELAXED,
                                            __HIP_MEMORY_SCOPE_AGENT);
                    if (!__any((unsigned)(kko & 0x7FFull) != tag)) break;
                }
            }

            // prefetch per-lane candidate coords, OVERLAPPED with key reduce
            const int idxc = 32767 - (int)((kko >> 17) & 0x7FFF);
            const float4 cand = p4[idxc];

            unsigned long long kk = kko;
            #pragma unroll
            for (int off = 1; off < 8; off <<= 1) {
                unsigned long long o = (unsigned long long)__shfl_xor((long long)kk, off, 64);
                if (o > kk) kk = o;
            }
            unsigned long long mask = __ballot(kko == kk);
            int src = (int)(__ffsll((unsigned long long)mask) - 1);
            cx = __shfl(cand.x, src, 64);
            cy = __shfl(cand.y, src, 64);
            cz = __shfl(cand.z, src, 64);

            if (lane == 0) {
                s_bc[0] = cx; s_bc[1] = cy; s_bc[2] = cz;
                __threadfence_block();               // coords visible before tag
                __hip_atomic_store(&s_tag, tag, __ATOMIC_RELAXED,
                                   __HIP_MEMORY_SCOPE_WORKGROUP);
                if (g == 0) {
                    int sel = 32767 - (int)((kk >> 17) & 0x7FFF);
                    out_idx[(size_t)b * S + s] = (float)sel;
                    idx_int[b * S + s] = sel;
                }
            }
        } else {
            while (__hip_atomic_load(&s_tag, __ATOMIC_RELAXED,
                                     __HIP_MEMORY_SCOPE_WORKGROUP) != tag) {}
            __threadfence_block();
            cx = s_bc[0]; cy = s_bc[1]; cz = s_bc[2];
        }
    }
}

// ---------------------------------------------------------------------------
// Ball query counts: one block (256 thr) per (batch, centroid).
// ---------------------------------------------------------------------------
__launch_bounds__(256)
__global__ void ballq_kernel(const float* __restrict__ ws,
                             const int* __restrict__ idx_int,
                             float* __restrict__ out_counts) {
    __shared__ int s_part[4];
    const int b = blockIdx.x >> 10;
    const int j = blockIdx.x & 1023;
    const int t = threadIdx.x;
    const float* __restrict__ px = ws + (size_t)b * N;
    const float* __restrict__ py = ws + (size_t)(B + b) * N;
    const float* __restrict__ pz = ws + (size_t)(2 * B + b) * N;

    const int ci = idx_int[b * S + j];
    const float cx = px[ci], cy = py[ci], cz = pz[ci];

    int cnt = 0;
    #pragma unroll 4
    for (int p = t; p < N; p += 256) {
        float dx = __fsub_rn(cx, px[p]);
        float dy = __fsub_rn(cy, py[p]);
        float dz = __fsub_rn(cz, pz[p]);
        float d2 = __fadd_rn(__fadd_rn(__fmul_rn(dx, dx), __fmul_rn(dy, dy)),
                             __fmul_rn(dz, dz));
        cnt += (d2 <= RAD2) ? 1 : 0;
    }
    #pragma unroll
    for (int off = 1; off < 64; off <<= 1)
        cnt += __shfl_xor(cnt, off, 64);
    if ((t & 63) == 0) s_part[t >> 6] = cnt;
    __syncthreads();
    if (t == 0)
        out_counts[b * S + j] = (float)(s_part[0] + s_part[1] + s_part[2] + s_part[3]);
}

// ---------------------------------------------------------------------------
extern "C" void kernel_launch(void* const* d_in, const int* in_sizes, int n_in,
                              void* d_out, int out_size, void* d_ws, size_t ws_size,
                              hipStream_t stream) {
    const float* x = (const float*)d_in[0];
    float* out = (float*)d_out;
    float* ws = (float*)d_ws;   // px|py|pz (3BN) | float4 pack (4BN) | idx ints | ctl | slots
    int* idx_int = (int*)(ws + (size_t)7 * B * N);
    unsigned* ctl = (unsigned*)(idx_int + B * S);                 // 128 u32 (512B)
    unsigned long long* slots_all = (unsigned long long*)(ctl + 128);

    float* out_x      = out;                         // B*N*D floats
    float* out_idx    = out + (size_t)B * N * D;     // B*S floats (idx as f32)
    float* out_counts = out_idx + (size_t)B * S;     // B*S floats (counts as f32)

    // zero ctl (512B) + slots (B*2*G*64B = 4KB) every launch
    hipMemsetAsync(ctl, 0,
                   512 + (size_t)B * 2 * G * SLOT_STRIDE * sizeof(unsigned long long),
                   stream);

    hipLaunchKernelGGL(pack_kernel, dim3((B * N + 255) / 256), dim3(256), 0, stream, x, ws);
    hipLaunchKernelGGL(fps_copy_kernel, dim3(NB_TOTAL), dim3(TPB), 0, stream,
                       x, ws, ctl, slots_all, out_idx, idx_int, out_x);
    hipLaunchKernelGGL(ballq_kernel, dim3(B * S), dim3(256), 0, stream, ws, idx_int, out_counts);
}

// Round 13
// 2004.315 us; speedup vs baseline: 1.5454x; 1.5454x over previous
//
#include <hip/hip_runtime.h>
#include <math.h>

#define B 4
#define N 32768
#define D 131
#define S 1024
#define RAD2 0.1f      // reference compares d2 <= RADIUS (=0.1) on SQUARED distance
#define G 16           // FPS blocks per batch
#define TPB 256        // threads per fps/copy block
#define PPT 8          // points per thread
#define NFPS (B * G)   // 64 fps blocks
#define COPY_BLOCKS 192
#define SLOT_STRIDE 8  // u64s per slot = 64B: one writer per L3 line (vs R9's packed 8B)

// ---------------------------------------------------------------------------
// Pack pts = x[:,:,:3] into SoA (px|py|pz) AND packed float4 {x,y,z,0}.
// ---------------------------------------------------------------------------
__global__ void pack_kernel(const float* __restrict__ x, float* __restrict__ ws) {
    int i = blockIdx.x * blockDim.x + threadIdx.x;
    if (i < B * N) {
        const float* __restrict__ s = x + (size_t)i * D;
        float a = s[0], bb = s[1], c = s[2];
        ws[i]             = a;
        ws[B * N + i]     = bb;
        ws[2 * B * N + i] = c;
        float4* w4 = (float4*)(ws + (size_t)3 * B * N);
        w4[i] = make_float4(a, bb, c, 0.0f);
    }
}

// ---------------------------------------------------------------------------
// Fused FPS + copy. 256 blocks x 256 thr. EXACTLY the R9 structure; the ONE
// change is 64B-strided sync slots (each block's slot on its own L3 line, so
// 16 near-simultaneous agent stores don't serialize on one line and pollers
// don't queue behind the write stream).
// FPS blocks [0,64): 16 blocks/batch, 8 pts/thread. Per step:
//   compute -> wave butterfly -> LDS wavekeys -> barrier -> blockkey ->
//   t0 stores slot (agent,relaxed,tagged) ->
//   WAVE0 ONLY: poll 16 slots (lane i -> slot (i&15), 64B stride; one load
//     issue/lane, 8 lines, pipelined), on success: prefetch per-lane
//     candidate coords p4[idx] OVERLAPPED with the 4-stage key reduce;
//     ballot -> shfl winner coords; lane0 publishes {cx,cy,cz}+tag to LDS.
//   OTHER WAVES: spin on LDS tag (no L3 traffic), fence, read coords.
// Copy blocks [64,256): grid-stride float4 copy of x (fps uses ~0 HBM BW).
// Key: [f32 val:32][32767-idx:15][0:6][tag=s+1:11]; equal tags => u64 max =
// (max val, then min idx) = exact reference tie-break.
// Slot double-buffer safety: buf overwritten at s+2 only after the writer's
// s+1 poll succeeded => every consumer finished reading step s.
// LDS tag safety: tag s+1 published only after barrier(s), which all waves
// reach only after consuming bcast(s-1); coords fenced before tag.
// ---------------------------------------------------------------------------
__launch_bounds__(TPB)
__global__ void fps_copy_kernel(const float* __restrict__ x,
                                const float* __restrict__ ws,
                                unsigned long long* __restrict__ gslot, // [B][2][G] 64B-strided
                                float* __restrict__ out_idx,
                                int* __restrict__ idx_int,
                                float* __restrict__ out_x) {
    if (blockIdx.x >= NFPS) {
        const size_t total4 = (size_t)B * N * D / 4;
        const float4* __restrict__ src = (const float4*)x;
        float4* __restrict__ dst = (float4*)out_x;
        for (size_t i = (size_t)(blockIdx.x - NFPS) * TPB + threadIdx.x; i < total4;
             i += (size_t)COPY_BLOCKS * TPB)
            dst[i] = src[i];
        return;
    }

    const int b = blockIdx.x >> 4;          // batch
    const int g = blockIdx.x & 15;          // participant id within batch
    const int t = threadIdx.x;
    const int lane = t & 63;
    const int w = t >> 6;                   // wave 0..3

    __shared__ unsigned long long s_wk[2][4];   // double-buffered wave keys
    __shared__ float s_bc[3];                   // broadcast centroid coords
    __shared__ unsigned s_tag;                  // monotone step tag

    const float* __restrict__ px = ws + (size_t)b * N;
    const float* __restrict__ py = ws + (size_t)(B + b) * N;
    const float* __restrict__ pz = ws + (size_t)(2 * B + b) * N;
    const float4* __restrict__ p4 = (const float4*)(ws + (size_t)3 * B * N) + (size_t)b * N;
    unsigned long long* __restrict__ slots = gslot + (size_t)b * 2 * G * SLOT_STRIDE;

    const int base = g * (N / G);
    float lx[PPT], ly[PPT], lz[PPT], lcl[PPT];
    #pragma unroll
    for (int i = 0; i < PPT / 2; ++i) {
        int p = base + 2 * t + 2 * TPB * i;
        float2 vx = *(const float2*)&px[p];
        float2 vy = *(const float2*)&py[p];
        float2 vz = *(const float2*)&pz[p];
        lx[2*i] = vx.x; lx[2*i+1] = vx.y;
        ly[2*i] = vy.x; ly[2*i+1] = vy.y;
        lz[2*i] = vz.x; lz[2*i+1] = vz.y;
        lcl[2*i] = INFINITY; lcl[2*i+1] = INFINITY;
    }
    if (t == 0) s_tag = 0;          // LDS is not zero-initialized
    __syncthreads();

    float4 cq = p4[0];
    float cx = cq.x, cy = cq.y, cz = cq.z;   // centroid 0 (ref starts at sel=0)

    for (int s = 0; s < S; ++s) {
        float best = -INFINITY;
        int   bidx = 0;
        #pragma unroll
        for (int i = 0; i < PPT / 2; ++i) {
            const int p = base + 2 * t + 2 * TPB * i;
            {
                float dx = __fsub_rn(cx, lx[2*i]);
                float dy = __fsub_rn(cy, ly[2*i]);
                float dz = __fsub_rn(cz, lz[2*i]);
                float d2 = __fadd_rn(__fadd_rn(__fmul_rn(dx, dx), __fmul_rn(dy, dy)),
                                     __fmul_rn(dz, dz));
                float c = fminf(lcl[2*i], d2);
                lcl[2*i] = c;
                if (c > best) { best = c; bidx = p; }     // strict >: smallest p wins
            }
            {
                float dx = __fsub_rn(cx, lx[2*i+1]);
                float dy = __fsub_rn(cy, ly[2*i+1]);
                float dz = __fsub_rn(cz, lz[2*i+1]);
                float d2 = __fadd_rn(__fadd_rn(__fmul_rn(dx, dx), __fmul_rn(dy, dy)),
                                     __fmul_rn(dz, dz));
                float c = fminf(lcl[2*i+1], d2);
                lcl[2*i+1] = c;
                if (c > best) { best = c; bidx = p + 1; }
            }
        }

        // intra-wave butterfly argmax on (value, smallest idx)
        unsigned hi  = __float_as_uint(best);
        unsigned lo2 = (unsigned)(32767 - bidx);
        #define FPS_COMBINE(OHI, OLO) \
            { unsigned _oh = (OHI), _ol = (OLO); \
              if (_oh > hi || (_oh == hi && _ol > lo2)) { hi = _oh; lo2 = _ol; } }
        { unsigned a = (unsigned)__builtin_amdgcn_update_dpp(0, (int)hi, 0xB1, 0xf, 0xf, true);
          unsigned c2 = (unsigned)__builtin_amdgcn_update_dpp(0, (int)lo2, 0xB1, 0xf, 0xf, true);
          FPS_COMBINE(a, c2); }
        { unsigned a = (unsigned)__builtin_amdgcn_update_dpp(0, (int)hi, 0x4E, 0xf, 0xf, true);
          unsigned c2 = (unsigned)__builtin_amdgcn_update_dpp(0, (int)lo2, 0x4E, 0xf, 0xf, true);
          FPS_COMBINE(a, c2); }
        { unsigned a = (unsigned)__builtin_amdgcn_update_dpp(0, (int)hi, 0x141, 0xf, 0xf, true);
          unsigned c2 = (unsigned)__builtin_amdgcn_update_dpp(0, (int)lo2, 0x141, 0xf, 0xf, true);
          FPS_COMBINE(a, c2); }
        { unsigned a = (unsigned)__builtin_amdgcn_update_dpp(0, (int)hi, 0x140, 0xf, 0xf, true);
          unsigned c2 = (unsigned)__builtin_amdgcn_update_dpp(0, (int)lo2, 0x140, 0xf, 0xf, true);
          FPS_COMBINE(a, c2); }
        { unsigned a = (unsigned)__builtin_amdgcn_ds_swizzle((int)hi, 0x401F);
          unsigned c2 = (unsigned)__builtin_amdgcn_ds_swizzle((int)lo2, 0x401F);
          FPS_COMBINE(a, c2); }
        { unsigned a = (unsigned)__shfl_xor((int)hi, 32, 64);
          unsigned c2 = (unsigned)__shfl_xor((int)lo2, 32, 64);
          FPS_COMBINE(a, c2); }
        #undef FPS_COMBINE

        const int buf = s & 1;
        const unsigned tag = (unsigned)(s + 1);
        const unsigned long long mykey = ((unsigned long long)hi << 32) |
                                         ((unsigned long long)lo2 << 17) | tag;
        if (lane == 0) s_wk[buf][w] = mykey;
        __syncthreads();                             // the ONLY barrier per step

        if (w == 0) {
            // block key = max of 4 wave keys
            unsigned long long bk = s_wk[buf][0];
            #pragma unroll
            for (int j = 1; j < 4; ++j) { unsigned long long v = s_wk[buf][j]; if (v > bk) bk = v; }
            if (lane == 0)
                __hip_atomic_store(&slots[((size_t)buf * G + g) * SLOT_STRIDE], bk,
                                   __ATOMIC_RELAXED, __HIP_MEMORY_SCOPE_AGENT);

            // poll 16 slots: lane i watches slot i&15 (64B stride -> 8 lines,
            // one load issue per lane, pipelined at L3)
            unsigned long long kk;
            unsigned long long* myslot = &slots[((size_t)buf * G + (lane & 15)) * SLOT_STRIDE];
            do {
                kk = __hip_atomic_load(myslot, __ATOMIC_RELAXED, __HIP_MEMORY_SCOPE_AGENT);
            } while (__any((unsigned)(kk & 0x7FFull) != tag));

            // prefetch per-lane candidate coords, OVERLAPPED with key reduce
            const unsigned long long kko = kk;
            const int idxc = 32767 - (int)((kko >> 17) & 0x7FFF);
            const float4 cand = p4[idxc];            // issued before the reduce

            #pragma unroll
            for (int off = 1; off < 16; off <<= 1) {
                unsigned long long o = (unsigned long long)__shfl_xor((long long)kk, off, 64);
                if (o > kk) kk = o;
            }
            // winning lane's prefetched coords
            unsigned long long mask = __ballot(kko == kk);
            int src = (int)(__ffsll((unsigned long long)mask) - 1);
            cx = __shfl(cand.x, src, 64);
            cy = __shfl(cand.y, src, 64);
            cz = __shfl(cand.z, src, 64);

            if (lane == 0) {
                s_bc[0] = cx; s_bc[1] = cy; s_bc[2] = cz;
                __threadfence_block();               // coords visible before tag
                __hip_atomic_store(&s_tag, tag, __ATOMIC_RELAXED,
                                   __HIP_MEMORY_SCOPE_WORKGROUP);
                if (g == 0) {
                    int sel = 32767 - (int)((kk >> 17) & 0x7FFF);
                    out_idx[(size_t)b * S + s] = (float)sel;
                    idx_int[b * S + s] = sel;
                }
            }
        } else {
            // spin on the local LDS tag (no global traffic), then read coords
            while (__hip_atomic_load(&s_tag, __ATOMIC_RELAXED,
                                     __HIP_MEMORY_SCOPE_WORKGROUP) != tag) {}
            __threadfence_block();
            cx = s_bc[0]; cy = s_bc[1]; cz = s_bc[2];
        }
    }
}

// ---------------------------------------------------------------------------
// Ball query counts: one block (256 thr) per (batch, centroid).
// ---------------------------------------------------------------------------
__launch_bounds__(256)
__global__ void ballq_kernel(const float* __restrict__ ws,
                             const int* __restrict__ idx_int,
                             float* __restrict__ out_counts) {
    __shared__ int s_part[4];
    const int b = blockIdx.x >> 10;
    const int j = blockIdx.x & 1023;
    const int t = threadIdx.x;
    const float* __restrict__ px = ws + (size_t)b * N;
    const float* __restrict__ py = ws + (size_t)(B + b) * N;
    const float* __restrict__ pz = ws + (size_t)(2 * B + b) * N;

    const int ci = idx_int[b * S + j];
    const float cx = px[ci], cy = py[ci], cz = pz[ci];

    int cnt = 0;
    #pragma unroll 4
    for (int p = t; p < N; p += 256) {
        float dx = __fsub_rn(cx, px[p]);
        float dy = __fsub_rn(cy, py[p]);
        float dz = __fsub_rn(cz, pz[p]);
        float d2 = __fadd_rn(__fadd_rn(__fmul_rn(dx, dx), __fmul_rn(dy, dy)),
                             __fmul_rn(dz, dz));
        cnt += (d2 <= RAD2) ? 1 : 0;
    }
    #pragma unroll
    for (int off = 1; off < 64; off <<= 1)
        cnt += __shfl_xor(cnt, off, 64);
    if ((t & 63) == 0) s_part[t >> 6] = cnt;
    __syncthreads();
    if (t == 0)
        out_counts[b * S + j] = (float)(s_part[0] + s_part[1] + s_part[2] + s_part[3]);
}

// ---------------------------------------------------------------------------
extern "C" void kernel_launch(void* const* d_in, const int* in_sizes, int n_in,
                              void* d_out, int out_size, void* d_ws, size_t ws_size,
                              hipStream_t stream) {
    const float* x = (const float*)d_in[0];
    float* out = (float*)d_out;
    float* ws = (float*)d_ws;   // px|py|pz (3BN) | float4 pack (4BN) | idx ints | slots
    int* idx_int = (int*)(ws + (size_t)7 * B * N);
    unsigned long long* gslot = (unsigned long long*)(idx_int + B * S);

    float* out_x      = out;                         // B*N*D floats
    float* out_idx    = out + (size_t)B * N * D;     // B*S floats (idx as f32)
    float* out_counts = out_idx + (size_t)B * S;     // B*S floats (counts as f32)

    // zero the padded slot array: B*2*G slots * 64B = 16 KB
    hipMemsetAsync(gslot, 0,
                   (size_t)B * 2 * G * SLOT_STRIDE * sizeof(unsigned long long), stream);

    hipLaunchKernelGGL(pack_kernel, dim3((B * N + 255) / 256), dim3(256), 0, stream, x, ws);
    hipLaunchKernelGGL(fps_copy_kernel, dim3(NFPS + COPY_BLOCKS), dim3(TPB), 0, stream,
                       x, ws, gslot, out_idx, idx_int, out_x);
    hipLaunchKernelGGL(ballq_kernel, dim3(B * S), dim3(256), 0, stream, ws, idx_int, out_counts);
}

// Round 14
// 1937.322 us; speedup vs baseline: 1.5988x; 1.0346x over previous
//
#include <hip/hip_runtime.h>
#include <math.h>

#define B 4
#define N 32768
#define D 131
#define S 1024
#define RAD2 0.1f      // reference compares d2 <= RADIUS (=0.1) on SQUARED distance
#define G 16           // FPS blocks per batch
#define TPB 256        // threads per fps/copy block
#define PPT 8          // points per thread
#define NFPS (B * G)   // 64 fps blocks
#define COPY_BLOCKS 192

// ---------------------------------------------------------------------------
// Pack pts = x[:,:,:3] into SoA (px|py|pz) AND packed float4 {x,y,z,0}.
// ---------------------------------------------------------------------------
__global__ void pack_kernel(const float* __restrict__ x, float* __restrict__ ws) {
    int i = blockIdx.x * blockDim.x + threadIdx.x;
    if (i < B * N) {
        const float* __restrict__ s = x + (size_t)i * D;
        float a = s[0], bb = s[1], c = s[2];
        ws[i]             = a;
        ws[B * N + i]     = bb;
        ws[2 * B * N + i] = c;
        float4* w4 = (float4*)(ws + (size_t)3 * B * N);
        w4[i] = make_float4(a, bb, c, 0.0f);
    }
}

// ---------------------------------------------------------------------------
// Fused FPS + copy — the measured-best configuration (R9: 1939 us total).
// Final form. Per-step cost ~4450 cyc is a cross-XCD rendezvous LATENCY floor:
// verified invariant across two-barrier funnel (R5), this barrier-free form
// (R9), padded slots (R13); all restructuring attempts (wave-granular R6,
// dual-chain R7, all-wave poll R8, staggered poll R10, sc0-L2 R11,
// XCD-verified groups R12) regressed.
// FPS blocks [0,64): 16 blocks/batch, 8 pts/thread. Per step:
//   compute -> wave butterfly -> LDS wavekeys -> barrier -> blockkey ->
//   t0 stores slot (agent,relaxed,tagged) ->
//   WAVE0 ONLY: poll 16 packed slots (lane i -> slot i&15, one coalesced
//     128B load/iter; 64 pollers chip-wide), on success: prefetch per-lane
//     candidate coords p4[idx] OVERLAPPED with the 4-stage key reduce;
//     ballot -> shfl winner coords; lane0 publishes {cx,cy,cz}+tag to LDS.
//   OTHER WAVES: spin on LDS tag (no L3 traffic), fence, read coords.
// Copy blocks [64,256): grid-stride float4 copy of x (fps uses ~0 HBM BW).
// Key: [f32 val:32][32767-idx:15][0:6][tag=s+1:11]; equal tags => u64 max =
// (max val, then min idx) = exact reference tie-break.
// Slot double-buffer safety: buf overwritten at s+2 only after the writer's
// s+1 poll succeeded => every consumer finished reading step s.
// LDS tag safety: tag s+1 published only after barrier(s), which all waves
// reach only after consuming bcast(s-1); coords fenced before tag.
// ---------------------------------------------------------------------------
__launch_bounds__(TPB)
__global__ void fps_copy_kernel(const float* __restrict__ x,
                                const float* __restrict__ ws,
                                unsigned long long* __restrict__ gslot, // [B][2][G] zeroed
                                float* __restrict__ out_idx,
                                int* __restrict__ idx_int,
                                float* __restrict__ out_x) {
    if (blockIdx.x >= NFPS) {
        const size_t total4 = (size_t)B * N * D / 4;
        const float4* __restrict__ src = (const float4*)x;
        float4* __restrict__ dst = (float4*)out_x;
        for (size_t i = (size_t)(blockIdx.x - NFPS) * TPB + threadIdx.x; i < total4;
             i += (size_t)COPY_BLOCKS * TPB)
            dst[i] = src[i];
        return;
    }

    const int b = blockIdx.x >> 4;          // batch
    const int g = blockIdx.x & 15;          // participant id within batch
    const int t = threadIdx.x;
    const int lane = t & 63;
    const int w = t >> 6;                   // wave 0..3

    __shared__ unsigned long long s_wk[2][4];   // double-buffered wave keys
    __shared__ float s_bc[3];                   // broadcast centroid coords
    __shared__ unsigned s_tag;                  // monotone step tag

    const float* __restrict__ px = ws + (size_t)b * N;
    const float* __restrict__ py = ws + (size_t)(B + b) * N;
    const float* __restrict__ pz = ws + (size_t)(2 * B + b) * N;
    const float4* __restrict__ p4 = (const float4*)(ws + (size_t)3 * B * N) + (size_t)b * N;
    unsigned long long* __restrict__ slots = gslot + (size_t)b * 2 * G;

    const int base = g * (N / G);
    float lx[PPT], ly[PPT], lz[PPT], lcl[PPT];
    #pragma unroll
    for (int i = 0; i < PPT / 2; ++i) {
        int p = base + 2 * t + 2 * TPB * i;
        float2 vx = *(const float2*)&px[p];
        float2 vy = *(const float2*)&py[p];
        float2 vz = *(const float2*)&pz[p];
        lx[2*i] = vx.x; lx[2*i+1] = vx.y;
        ly[2*i] = vy.x; ly[2*i+1] = vy.y;
        lz[2*i] = vz.x; lz[2*i+1] = vz.y;
        lcl[2*i] = INFINITY; lcl[2*i+1] = INFINITY;
    }
    if (t == 0) s_tag = 0;          // LDS is not zero-initialized
    __syncthreads();

    float4 cq = p4[0];
    float cx = cq.x, cy = cq.y, cz = cq.z;   // centroid 0 (ref starts at sel=0)

    for (int s = 0; s < S; ++s) {
        float best = -INFINITY;
        int   bidx = 0;
        #pragma unroll
        for (int i = 0; i < PPT / 2; ++i) {
            const int p = base + 2 * t + 2 * TPB * i;
            {
                float dx = __fsub_rn(cx, lx[2*i]);
                float dy = __fsub_rn(cy, ly[2*i]);
                float dz = __fsub_rn(cz, lz[2*i]);
                float d2 = __fadd_rn(__fadd_rn(__fmul_rn(dx, dx), __fmul_rn(dy, dy)),
                                     __fmul_rn(dz, dz));
                float c = fminf(lcl[2*i], d2);
                lcl[2*i] = c;
                if (c > best) { best = c; bidx = p; }     // strict >: smallest p wins
            }
            {
                float dx = __fsub_rn(cx, lx[2*i+1]);
                float dy = __fsub_rn(cy, ly[2*i+1]);
                float dz = __fsub_rn(cz, lz[2*i+1]);
                float d2 = __fadd_rn(__fadd_rn(__fmul_rn(dx, dx), __fmul_rn(dy, dy)),
                                     __fmul_rn(dz, dz));
                float c = fminf(lcl[2*i+1], d2);
                lcl[2*i+1] = c;
                if (c > best) { best = c; bidx = p + 1; }
            }
        }

        // intra-wave butterfly argmax on (value, smallest idx)
        unsigned hi  = __float_as_uint(best);
        unsigned lo2 = (unsigned)(32767 - bidx);
        #define FPS_COMBINE(OHI, OLO) \
            { unsigned _oh = (OHI), _ol = (OLO); \
              if (_oh > hi || (_oh == hi && _ol > lo2)) { hi = _oh; lo2 = _ol; } }
        { unsigned a = (unsigned)__builtin_amdgcn_update_dpp(0, (int)hi, 0xB1, 0xf, 0xf, true);
          unsigned c2 = (unsigned)__builtin_amdgcn_update_dpp(0, (int)lo2, 0xB1, 0xf, 0xf, true);
          FPS_COMBINE(a, c2); }
        { unsigned a = (unsigned)__builtin_amdgcn_update_dpp(0, (int)hi, 0x4E, 0xf, 0xf, true);
          unsigned c2 = (unsigned)__builtin_amdgcn_update_dpp(0, (int)lo2, 0x4E, 0xf, 0xf, true);
          FPS_COMBINE(a, c2); }
        { unsigned a = (unsigned)__builtin_amdgcn_update_dpp(0, (int)hi, 0x141, 0xf, 0xf, true);
          unsigned c2 = (unsigned)__builtin_amdgcn_update_dpp(0, (int)lo2, 0x141, 0xf, 0xf, true);
          FPS_COMBINE(a, c2); }
        { unsigned a = (unsigned)__builtin_amdgcn_update_dpp(0, (int)hi, 0x140, 0xf, 0xf, true);
          unsigned c2 = (unsigned)__builtin_amdgcn_update_dpp(0, (int)lo2, 0x140, 0xf, 0xf, true);
          FPS_COMBINE(a, c2); }
        { unsigned a = (unsigned)__builtin_amdgcn_ds_swizzle((int)hi, 0x401F);
          unsigned c2 = (unsigned)__builtin_amdgcn_ds_swizzle((int)lo2, 0x401F);
          FPS_COMBINE(a, c2); }
        { unsigned a = (unsigned)__shfl_xor((int)hi, 32, 64);
          unsigned c2 = (unsigned)__shfl_xor((int)lo2, 32, 64);
          FPS_COMBINE(a, c2); }
        #undef FPS_COMBINE

        const int buf = s & 1;
        const unsigned tag = (unsigned)(s + 1);
        const unsigned long long mykey = ((unsigned long long)hi << 32) |
                                         ((unsigned long long)lo2 << 17) | tag;
        if (lane == 0) s_wk[buf][w] = mykey;
        __syncthreads();                             // the ONLY barrier per step

        if (w == 0) {
            // block key = max of 4 wave keys
            unsigned long long bk = s_wk[buf][0];
            #pragma unroll
            for (int j = 1; j < 4; ++j) { unsigned long long v = s_wk[buf][j]; if (v > bk) bk = v; }
            if (lane == 0)
                __hip_atomic_store(&slots[buf * G + g], bk, __ATOMIC_RELAXED,
                                   __HIP_MEMORY_SCOPE_AGENT);

            // poll 16 slots: lane i watches slot i&15 (one coalesced 128B load/iter)
            unsigned long long kk;
            unsigned long long* myslot = &slots[buf * G + (lane & 15)];
            do {
                kk = __hip_atomic_load(myslot, __ATOMIC_RELAXED, __HIP_MEMORY_SCOPE_AGENT);
            } while (__any((unsigned)(kk & 0x7FFull) != tag));

            // prefetch per-lane candidate coords, OVERLAPPED with key reduce
            const unsigned long long kko = kk;
            const int idxc = 32767 - (int)((kko >> 17) & 0x7FFF);
            const float4 cand = p4[idxc];            // issued before the reduce

            #pragma unroll
            for (int off = 1; off < 16; off <<= 1) {
                unsigned long long o = (unsigned long long)__shfl_xor((long long)kk, off, 64);
                if (o > kk) kk = o;
            }
            // winning lane's prefetched coords
            unsigned long long mask = __ballot(kko == kk);
            int src = (int)(__ffsll((unsigned long long)mask) - 1);
            cx = __shfl(cand.x, src, 64);
            cy = __shfl(cand.y, src, 64);
            cz = __shfl(cand.z, src, 64);

            if (lane == 0) {
                s_bc[0] = cx; s_bc[1] = cy; s_bc[2] = cz;
                __threadfence_block();               // coords visible before tag
                __hip_atomic_store(&s_tag, tag, __ATOMIC_RELAXED,
                                   __HIP_MEMORY_SCOPE_WORKGROUP);
                if (g == 0) {
                    int sel = 32767 - (int)((kk >> 17) & 0x7FFF);
                    out_idx[(size_t)b * S + s] = (float)sel;
                    idx_int[b * S + s] = sel;
                }
            }
        } else {
            // spin on the local LDS tag (no global traffic), then read coords
            while (__hip_atomic_load(&s_tag, __ATOMIC_RELAXED,
                                     __HIP_MEMORY_SCOPE_WORKGROUP) != tag) {}
            __threadfence_block();
            cx = s_bc[0]; cy = s_bc[1]; cz = s_bc[2];
        }
    }
}

// ---------------------------------------------------------------------------
// Ball query counts: one block (256 thr) per (batch, centroid).
// ---------------------------------------------------------------------------
__launch_bounds__(256)
__global__ void ballq_kernel(const float* __restrict__ ws,
                             const int* __restrict__ idx_int,
                             float* __restrict__ out_counts) {
    __shared__ int s_part[4];
    const int b = blockIdx.x >> 10;
    const int j = blockIdx.x & 1023;
    const int t = threadIdx.x;
    const float* __restrict__ px = ws + (size_t)b * N;
    const float* __restrict__ py = ws + (size_t)(B + b) * N;
    const float* __restrict__ pz = ws + (size_t)(2 * B + b) * N;

    const int ci = idx_int[b * S + j];
    const float cx = px[ci], cy = py[ci], cz = pz[ci];

    int cnt = 0;
    #pragma unroll 4
    for (int p = t; p < N; p += 256) {
        float dx = __fsub_rn(cx, px[p]);
        float dy = __fsub_rn(cy, py[p]);
        float dz = __fsub_rn(cz, pz[p]);
        float d2 = __fadd_rn(__fadd_rn(__fmul_rn(dx, dx), __fmul_rn(dy, dy)),
                             __fmul_rn(dz, dz));
        cnt += (d2 <= RAD2) ? 1 : 0;
    }
    #pragma unroll
    for (int off = 1; off < 64; off <<= 1)
        cnt += __shfl_xor(cnt, off, 64);
    if ((t & 63) == 0) s_part[t >> 6] = cnt;
    __syncthreads();
    if (t == 0)
        out_counts[b * S + j] = (float)(s_part[0] + s_part[1] + s_part[2] + s_part[3]);
}

// ---------------------------------------------------------------------------
extern "C" void kernel_launch(void* const* d_in, const int* in_sizes, int n_in,
                              void* d_out, int out_size, void* d_ws, size_t ws_size,
                              hipStream_t stream) {
    const float* x = (const float*)d_in[0];
    float* out = (float*)d_out;
    float* ws = (float*)d_ws;   // px|py|pz (3BN) | float4 pack (4BN) | idx ints | slots
    int* idx_int = (int*)(ws + (size_t)7 * B * N);
    unsigned long long* gslot = (unsigned long long*)(idx_int + B * S);

    float* out_x      = out;                         // B*N*D floats
    float* out_idx    = out + (size_t)B * N * D;     // B*S floats (idx as f32)
    float* out_counts = out_idx + (size_t)B * S;     // B*S floats (counts as f32)

    hipMemsetAsync(gslot, 0, (size_t)B * 2 * G * sizeof(unsigned long long), stream);

    hipLaunchKernelGGL(pack_kernel, dim3((B * N + 255) / 256), dim3(256), 0, stream, x, ws);
    hipLaunchKernelGGL(fps_copy_kernel, dim3(NFPS + COPY_BLOCKS), dim3(TPB), 0, stream,
                       x, ws, gslot, out_idx, idx_int, out_x);
    hipLaunchKernelGGL(ballq_kernel, dim3(B * S), dim3(256), 0, stream, ws, idx_int, out_counts);
}